// Round 1
// baseline (489.478 us; speedup 1.0000x reference)
//
#include <hip/hip_runtime.h>

// ---- problem constants ----
#define BB 2
#define SS 1024
#define HIDDEN 2880
#define NH 64
#define NKV 8
#define HD 64
#define M_TOK 2048          // B*S
#define NQ 4096             // NH*HD
#define NKVD 512            // NKV*HD
#define NQKV 5120           // NQ + 2*NKVD
#define NOUT 2880
#define NOUT_PAD 2944       // 23*128

typedef __attribute__((ext_vector_type(8))) short short8;
typedef __attribute__((ext_vector_type(4))) float f32x4;

__device__ __forceinline__ unsigned short f2b(float x) {
  union { float f; unsigned u; } v; v.f = x;
  unsigned r = (v.u + 0x7FFFu + ((v.u >> 16) & 1u)) >> 16;
  return (unsigned short)r;
}

__device__ __forceinline__ void gload16(const void* g, void* l) {
  __builtin_amdgcn_global_load_lds(
      (const __attribute__((address_space(1))) void*)g,
      (__attribute__((address_space(3))) void*)l, 16, 0, 0);
}

// ---- cast x (fp32 -> bf16), vectorized ----
__global__ __launch_bounds__(256) void cast_x_kernel(const float* __restrict__ in,
                                                     unsigned short* __restrict__ out,
                                                     int n4) {
  int idx = blockIdx.x * 256 + threadIdx.x;
  if (idx >= n4) return;
  float4 v = ((const float4*)in)[idx];
  ushort4 o;
  o.x = f2b(v.x); o.y = f2b(v.y); o.z = f2b(v.z); o.w = f2b(v.w);
  ((ushort4*)out)[idx] = o;
}

// ---- transpose + cast: out[n*K + k] = (bf16) in[k*ldin + n] ----
// grid: (Npad/32, K/32), block (32,8). K must be multiple of 32. n>=N -> 0.
__global__ __launch_bounds__(256) void transpose_cast(const float* __restrict__ in,
                                                      long ldin,
                                                      unsigned short* __restrict__ out,
                                                      int K, int N) {
  __shared__ float t[32][33];
  const int n0 = blockIdx.x * 32, k0 = blockIdx.y * 32;
  const int tx = threadIdx.x, ty = threadIdx.y;
#pragma unroll
  for (int i = 0; i < 4; ++i) {
    int k = k0 + ty + i * 8;
    int n = n0 + tx;
    t[ty + i * 8][tx] = (n < N) ? in[(long)k * ldin + n] : 0.f;
  }
  __syncthreads();
#pragma unroll
  for (int i = 0; i < 4; ++i) {
    int n = n0 + ty + i * 8;
    int k = k0 + tx;
    out[(long)n * K + k] = f2b(t[tx][ty + i * 8]);
  }
}

// ---- RoPE cos/sin table: [2048][32] each ----
__global__ __launch_bounds__(256) void rope_table(const int* __restrict__ pos,
                                                  float* __restrict__ ct,
                                                  float* __restrict__ st) {
  int tid = blockIdx.x * 256 + threadIdx.x;   // < 2048*32
  int t = tid >> 5, i = tid & 31;
  float p = (float)pos[t];
  // inv_freq = theta^(-i/32), theta = 150000 ; log(150000) = 11.9183905730784
  float f = p * expf(-(float)i * (11.918390573078392f / 32.f));
  ct[tid] = cosf(f);
  st[tid] = sinf(f);
}

// ---- RoPE + pack q: qkvf[t][h*64+d] -> qb[b][h][s][d] bf16 ----
__global__ __launch_bounds__(256) void rope_q_pack(const float* __restrict__ qkvf,
                                                   const float* __restrict__ ct,
                                                   const float* __restrict__ st,
                                                   unsigned short* __restrict__ qb) {
  int tid = blockIdx.x * 256 + threadIdx.x;   // < 2048*64*32
  int i = tid & 31;
  int h = (tid >> 5) & 63;
  int t = tid >> 11;
  const float* src = qkvf + (size_t)t * NQKV + h * 64;
  float x1 = src[i], x2 = src[i + 32];
  float c = ct[t * 32 + i], s = st[t * 32 + i];
  int b = t >> 10, sidx = t & 1023;
  unsigned short* dst = qb + (((size_t)(b * NH + h)) * SS + sidx) * HD;
  dst[i]      = f2b(x1 * c - x2 * s);
  dst[i + 32] = f2b(x1 * s + x2 * c);
}

// ---- RoPE + pack k ----
__global__ __launch_bounds__(256) void rope_k_pack(const float* __restrict__ qkvf,
                                                   const float* __restrict__ ct,
                                                   const float* __restrict__ st,
                                                   unsigned short* __restrict__ kb) {
  int tid = blockIdx.x * 256 + threadIdx.x;   // < 2048*8*32
  int i = tid & 31;
  int h = (tid >> 5) & 7;
  int t = tid >> 8;
  const float* src = qkvf + (size_t)t * NQKV + NQ + h * 64;
  float x1 = src[i], x2 = src[i + 32];
  float c = ct[t * 32 + i], s = st[t * 32 + i];
  int b = t >> 10, sidx = t & 1023;
  unsigned short* dst = kb + (((size_t)(b * NKV + h)) * SS + sidx) * HD;
  dst[i]      = f2b(x1 * c - x2 * s);
  dst[i + 32] = f2b(x1 * s + x2 * c);
}

// ---- GEMM: C[M][ldc] (fp32) = A_bf16[M][K] * Bt_bf16[N][K]^T  (m97 structure) ----
// grid (N/128, M/128), block 256. K % 32 == 0.
__global__ __launch_bounds__(256) void gemm_bt(const unsigned short* __restrict__ A,
                                               const unsigned short* __restrict__ Bt,
                                               float* __restrict__ C,
                                               int K, int ldc, int Nvalid) {
  __shared__ unsigned short lA[128 * 32];
  __shared__ unsigned short lB[128 * 32];
  const int tid = threadIdx.x;
  const int lane = tid & 63;
  const int w = tid >> 6;
  const int wm = (w >> 1) * 64, wn = (w & 1) * 64;
  const int bm = blockIdx.y * 128, bn = blockIdx.x * 128;
  const int m16 = lane & 15, g4 = lane >> 4;
  f32x4 acc[4][4];
#pragma unroll
  for (int i = 0; i < 4; ++i)
#pragma unroll
    for (int j = 0; j < 4; ++j) acc[i][j] = (f32x4){0.f, 0.f, 0.f, 0.f};
  const int srow = tid >> 2;
  const int scol = (tid & 3) * 8;
  const unsigned short* ga = A + (size_t)(bm + srow) * K + scol;
  const unsigned short* gb = Bt + (size_t)(bn + srow) * K + scol;
  const int lw = (tid >> 6) * 512;   // wave-uniform LDS elem offset
  const int nk = K >> 5;
  for (int kt = 0; kt < nk; ++kt) {
    const int ko = kt * 32;
    __syncthreads();
    gload16(ga + ko,                  lA + lw);
    gload16(ga + (size_t)64 * K + ko, lA + 2048 + lw);
    gload16(gb + ko,                  lB + lw);
    gload16(gb + (size_t)64 * K + ko, lB + 2048 + lw);
    __syncthreads();
    short8 af[4], bfr[4];
#pragma unroll
    for (int mi = 0; mi < 4; ++mi)
      af[mi] = *(const short8*)(lA + (wm + mi * 16 + m16) * 32 + g4 * 8);
#pragma unroll
    for (int ni = 0; ni < 4; ++ni)
      bfr[ni] = *(const short8*)(lB + (wn + ni * 16 + m16) * 32 + g4 * 8);
#pragma unroll
    for (int mi = 0; mi < 4; ++mi)
#pragma unroll
      for (int ni = 0; ni < 4; ++ni)
        acc[mi][ni] = __builtin_amdgcn_mfma_f32_16x16x32_bf16(af[mi], bfr[ni], acc[mi][ni], 0, 0, 0);
  }
  const int r0 = g4 * 4;
#pragma unroll
  for (int mi = 0; mi < 4; ++mi)
#pragma unroll
    for (int ni = 0; ni < 4; ++ni) {
      const int col = bn + wn + ni * 16 + m16;
      if (col < Nvalid) {
        const int row = bm + wm + mi * 16 + r0;
#pragma unroll
        for (int r = 0; r < 4; ++r)
          C[(size_t)(row + r) * ldc + col] = acc[mi][ni][r];
      }
    }
}

// ---- flash attention (causal, GQA) ----
// grid (16 q-tiles, 128 b*h), block 256 (4 waves x 16 q-rows each).
// qb [B][NH][S][64], kb [B][NKV][S][64], vtb [B][NKV][64][S] all bf16.
// out ao [2048][4096] bf16 (row = b*S+s, col = h*64+d).
__global__ __launch_bounds__(256) void attn_fwd(const unsigned short* __restrict__ qb,
                                                const unsigned short* __restrict__ kb,
                                                const unsigned short* __restrict__ vtb,
                                                unsigned short* __restrict__ ao) {
  __shared__ unsigned short pl[4][16 * 32];
  const int tid = threadIdx.x, lane = tid & 63, w = tid >> 6;
  const int qt = blockIdx.x;
  const int bh = blockIdx.y;
  const int b = bh >> 6, h = bh & 63, hkv = h >> 3;
  const int m16 = lane & 15, g4 = lane >> 4;
  const int qrow0 = qt * 64 + w * 16;

  const unsigned short* qp =
      qb + (((size_t)(b * NH + h)) * SS + qrow0 + m16) * HD + g4 * 8;
  short8 q0 = *(const short8*)(qp);
  short8 q1 = *(const short8*)(qp + 32);
  const unsigned short* kbp = kb + ((size_t)(b * NKV + hkv)) * SS * HD;
  const unsigned short* vbp = vtb + ((size_t)(b * NKV + hkv)) * HD * SS;

  f32x4 o[4];
#pragma unroll
  for (int n = 0; n < 4; ++n) o[n] = (f32x4){0.f, 0.f, 0.f, 0.f};
  float mrow[4] = {-1e30f, -1e30f, -1e30f, -1e30f};
  float lrow[4] = {0.f, 0.f, 0.f, 0.f};
  const int rbase = qrow0 + g4 * 4;
  const int nt = qt * 2 + 2;

  for (int t = 0; t < nt; ++t) {
    const int k0 = t * 32;
    f32x4 s0, s1;
    {
      const unsigned short* kr = kbp + (size_t)(k0 + m16) * HD + g4 * 8;
      short8 ka = *(const short8*)(kr);
      short8 kc = *(const short8*)(kr + 32);
      f32x4 z = (f32x4){0.f, 0.f, 0.f, 0.f};
      z = __builtin_amdgcn_mfma_f32_16x16x32_bf16(q0, ka, z, 0, 0, 0);
      z = __builtin_amdgcn_mfma_f32_16x16x32_bf16(q1, kc, z, 0, 0, 0);
      s0 = z;
      kr += 16 * HD;
      ka = *(const short8*)(kr);
      kc = *(const short8*)(kr + 32);
      z = (f32x4){0.f, 0.f, 0.f, 0.f};
      z = __builtin_amdgcn_mfma_f32_16x16x32_bf16(q0, ka, z, 0, 0, 0);
      z = __builtin_amdgcn_mfma_f32_16x16x32_bf16(q1, kc, z, 0, 0, 0);
      s1 = z;
    }
    // scale + causal mask (score row = rbase+r, col = k0 [+16] + m16)
#pragma unroll
    for (int r = 0; r < 4; ++r) {
      s0[r] *= 0.125f;
      s1[r] *= 0.125f;
      if (k0 + m16 > rbase + r)      s0[r] = -1e30f;
      if (k0 + 16 + m16 > rbase + r) s1[r] = -1e30f;
    }
    // row max over the 16 lanes of this group
    float mx[4];
#pragma unroll
    for (int r = 0; r < 4; ++r) mx[r] = fmaxf(s0[r], s1[r]);
#pragma unroll
    for (int off = 1; off <= 8; off <<= 1)
#pragma unroll
      for (int r = 0; r < 4; ++r) mx[r] = fmaxf(mx[r], __shfl_xor(mx[r], off));

    float p0[4], p1[4], rs[4];
#pragma unroll
    for (int r = 0; r < 4; ++r) {
      float mn = fmaxf(mrow[r], mx[r]);
      float sc = __expf(mrow[r] - mn);
      mrow[r] = mn;
      p0[r] = __expf(s0[r] - mn);
      p1[r] = __expf(s1[r] - mn);
      rs[r] = p0[r] + p1[r];
      lrow[r] *= sc;
#pragma unroll
      for (int n = 0; n < 4; ++n) o[n][r] *= sc;
    }
#pragma unroll
    for (int off = 1; off <= 8; off <<= 1)
#pragma unroll
      for (int r = 0; r < 4; ++r) rs[r] += __shfl_xor(rs[r], off);
#pragma unroll
    for (int r = 0; r < 4; ++r) lrow[r] += rs[r];

    // P (C-layout) -> LDS -> A-frag layout
    unsigned short* pw = pl[w];
#pragma unroll
    for (int r = 0; r < 4; ++r) {
      pw[(g4 * 4 + r) * 32 + m16]      = f2b(p0[r]);
      pw[(g4 * 4 + r) * 32 + 16 + m16] = f2b(p1[r]);
    }
    __syncthreads();
    short8 pf = *(const short8*)(pw + m16 * 32 + g4 * 8);
#pragma unroll
    for (int n = 0; n < 4; ++n) {
      const unsigned short* vr = vbp + (size_t)(n * 16 + m16) * SS + k0 + g4 * 8;
      short8 vf = *(const short8*)(vr);
      o[n] = __builtin_amdgcn_mfma_f32_16x16x32_bf16(pf, vf, o[n], 0, 0, 0);
    }
    __syncthreads();
  }

  float inv[4];
#pragma unroll
  for (int r = 0; r < 4; ++r) inv[r] = 1.f / lrow[r];
  const size_t row0 = (size_t)b * SS + qt * 64 + w * 16 + g4 * 4;
#pragma unroll
  for (int n = 0; n < 4; ++n)
#pragma unroll
    for (int r = 0; r < 4; ++r)
      ao[(row0 + r) * (size_t)NQ + h * 64 + n * 16 + m16] = f2b(o[n][r] * inv[r]);
}

// ---- workspace layout (bytes) ----
constexpr size_t OFF_XB    = 0;                          // 2048*2880*2   = 11796480
constexpr size_t OFF_WQKVT = 11796480;                   // 5120*2880*2   = 29491200
constexpr size_t OFF_WOT   = OFF_WQKVT + 29491200;       // 2944*4096*2   = 24117248
constexpr size_t OFF_COS   = OFF_WOT + 24117248;         // 2048*32*4     = 262144
constexpr size_t OFF_SIN   = OFF_COS + 262144;
constexpr size_t OFF_QKVF  = OFF_SIN + 262144;           // 2048*5120*4   = 41943040
constexpr size_t OFF_QB    = OFF_QKVF + 41943040;        // 2*64*1024*64*2 = 16777216
constexpr size_t OFF_KB    = OFF_QB + 16777216;          // 2*8*1024*64*2  = 2097152
constexpr size_t OFF_VTB   = OFF_KB + 2097152;           // 2097152; end = 128843776

extern "C" void kernel_launch(void* const* d_in, const int* in_sizes, int n_in,
                              void* d_out, int out_size, void* d_ws, size_t ws_size,
                              hipStream_t stream) {
  const float* x  = (const float*)d_in[0];
  const float* wq = (const float*)d_in[1];
  const float* wk = (const float*)d_in[2];
  const float* wv = (const float*)d_in[3];
  const float* wo = (const float*)d_in[4];
  const int* pos  = (const int*)d_in[5];
  float* out = (float*)d_out;
  char* ws = (char*)d_ws;

  unsigned short* xb    = (unsigned short*)(ws + OFF_XB);
  unsigned short* wqkvt = (unsigned short*)(ws + OFF_WQKVT);
  unsigned short* wot   = (unsigned short*)(ws + OFF_WOT);
  float* ct             = (float*)(ws + OFF_COS);
  float* st             = (float*)(ws + OFF_SIN);
  float* qkvf           = (float*)(ws + OFF_QKVF);
  unsigned short* qb    = (unsigned short*)(ws + OFF_QB);
  unsigned short* kb    = (unsigned short*)(ws + OFF_KB);
  unsigned short* vtb   = (unsigned short*)(ws + OFF_VTB);
  unsigned short* attnb = (unsigned short*)(ws + OFF_QKVF);  // reuse qkvf region

  // 1. cast x to bf16
  cast_x_kernel<<<(M_TOK * HIDDEN / 4 + 255) / 256, 256, 0, stream>>>(x, xb, M_TOK * HIDDEN / 4);
  // 2. RoPE table
  rope_table<<<(M_TOK * 32) / 256, 256, 0, stream>>>(pos, ct, st);
  // 3. weight transposes (bf16, B^T layout)
  transpose_cast<<<dim3(NQ / 32, HIDDEN / 32), dim3(32, 8), 0, stream>>>(
      wq, NQ, wqkvt, HIDDEN, NQ);
  transpose_cast<<<dim3(NKVD / 32, HIDDEN / 32), dim3(32, 8), 0, stream>>>(
      wk, NKVD, wqkvt + (size_t)NQ * HIDDEN, HIDDEN, NKVD);
  transpose_cast<<<dim3(NKVD / 32, HIDDEN / 32), dim3(32, 8), 0, stream>>>(
      wv, NKVD, wqkvt + (size_t)(NQ + NKVD) * HIDDEN, HIDDEN, NKVD);
  transpose_cast<<<dim3(NOUT_PAD / 32, NQ / 32), dim3(32, 8), 0, stream>>>(
      wo, NOUT, wot, NQ, NOUT);
  // 4. fused QKV projection: [2048][5120] fp32
  gemm_bt<<<dim3(NQKV / 128, M_TOK / 128), 256, 0, stream>>>(
      xb, wqkvt, qkvf, HIDDEN, NQKV, NQKV);
  // 5. RoPE + pack q/k ; transpose-pack v
  rope_q_pack<<<(M_TOK * NH * 32) / 256, 256, 0, stream>>>(qkvf, ct, st, qb);
  rope_k_pack<<<(M_TOK * NKV * 32) / 256, 256, 0, stream>>>(qkvf, ct, st, kb);
  for (int b = 0; b < BB; ++b)
    transpose_cast<<<dim3(NKVD / 32, SS / 32), dim3(32, 8), 0, stream>>>(
        qkvf + (size_t)b * SS * NQKV + (NQ + NKVD), NQKV,
        vtb + (size_t)b * NKVD * SS, SS, NKVD);
  // 6. attention -> attnb [2048][4096] bf16 (aliases qkvf, which is dead now)
  attn_fwd<<<dim3(SS / 64, BB * NH), 256, 0, stream>>>(qb, kb, vtb, attnb);
  // 7. output projection -> d_out fp32 [2048][2880]
  gemm_bt<<<dim3(NOUT_PAD / 128, M_TOK / 128), 256, 0, stream>>>(
      attnb, wot, out, NQ, NOUT, NOUT);
}

// Round 2
// 487.758 us; speedup vs baseline: 1.0035x; 1.0035x over previous
//
#include <hip/hip_runtime.h>

// ---- problem constants ----
#define BB 2
#define SS 1024
#define HIDDEN 2880
#define NH 64
#define NKV 8
#define HD 64
#define M_TOK 2048          // B*S
#define NQ 4096             // NH*HD
#define NKVD 512            // NKV*HD
#define NQKV 5120           // NQ + 2*NKVD
#define NOUT 2880
#define NOUT_PAD 2944       // 23*128

typedef __attribute__((ext_vector_type(8))) short short8;
typedef __attribute__((ext_vector_type(4))) float f32x4;

__device__ __forceinline__ unsigned short f2b(float x) {
  union { float f; unsigned u; } v; v.f = x;
  unsigned r = (v.u + 0x7FFFu + ((v.u >> 16) & 1u)) >> 16;
  return (unsigned short)r;
}

__device__ __forceinline__ void gload16(const void* g, void* l) {
  __builtin_amdgcn_global_load_lds(
      (const __attribute__((address_space(1))) void*)g,
      (__attribute__((address_space(3))) void*)l, 16, 0, 0);
}

// ---- cast x (fp32 -> bf16), vectorized ----
__global__ __launch_bounds__(256) void cast_x_kernel(const float* __restrict__ in,
                                                     unsigned short* __restrict__ out,
                                                     int n4) {
  int idx = blockIdx.x * 256 + threadIdx.x;
  if (idx >= n4) return;
  float4 v = ((const float4*)in)[idx];
  ushort4 o;
  o.x = f2b(v.x); o.y = f2b(v.y); o.z = f2b(v.z); o.w = f2b(v.w);
  ((ushort4*)out)[idx] = o;
}

// ---- transpose + cast: out[n*K + k] = (bf16) in[k*ldin + n] ----
// grid: (Npad/32, K/32), block (32,8). K must be multiple of 32. n>=N -> 0.
__global__ __launch_bounds__(256) void transpose_cast(const float* __restrict__ in,
                                                      long ldin,
                                                      unsigned short* __restrict__ out,
                                                      int K, int N) {
  __shared__ float t[32][33];
  const int n0 = blockIdx.x * 32, k0 = blockIdx.y * 32;
  const int tx = threadIdx.x, ty = threadIdx.y;
#pragma unroll
  for (int i = 0; i < 4; ++i) {
    int k = k0 + ty + i * 8;
    int n = n0 + tx;
    t[ty + i * 8][tx] = (n < N) ? in[(long)k * ldin + n] : 0.f;
  }
  __syncthreads();
#pragma unroll
  for (int i = 0; i < 4; ++i) {
    int n = n0 + ty + i * 8;
    int k = k0 + tx;
    out[(long)n * K + k] = f2b(t[tx][ty + i * 8]);
  }
}

// ---- RoPE cos/sin table: [2048][32] each ----
__global__ __launch_bounds__(256) void rope_table(const int* __restrict__ pos,
                                                  float* __restrict__ ct,
                                                  float* __restrict__ st) {
  int tid = blockIdx.x * 256 + threadIdx.x;   // < 2048*32
  int t = tid >> 5, i = tid & 31;
  float p = (float)pos[t];
  float f = p * expf(-(float)i * (11.918390573078392f / 32.f));
  ct[tid] = cosf(f);
  st[tid] = sinf(f);
}

// ---- RoPE + pack q (pre-scaled by 1/8 for attention): -> qb[b][h][s][d] bf16 ----
__global__ __launch_bounds__(256) void rope_q_pack(const float* __restrict__ qkvf,
                                                   const float* __restrict__ ct,
                                                   const float* __restrict__ st,
                                                   unsigned short* __restrict__ qb) {
  int tid = blockIdx.x * 256 + threadIdx.x;   // < 2048*64*32
  int i = tid & 31;
  int h = (tid >> 5) & 63;
  int t = tid >> 11;
  const float* src = qkvf + (size_t)t * NQKV + h * 64;
  float x1 = src[i], x2 = src[i + 32];
  float c = ct[t * 32 + i], s = st[t * 32 + i];
  int b = t >> 10, sidx = t & 1023;
  unsigned short* dst = qb + (((size_t)(b * NH + h)) * SS + sidx) * HD;
  dst[i]      = f2b((x1 * c - x2 * s) * 0.125f);
  dst[i + 32] = f2b((x1 * s + x2 * c) * 0.125f);
}

// ---- RoPE + pack k ----
__global__ __launch_bounds__(256) void rope_k_pack(const float* __restrict__ qkvf,
                                                   const float* __restrict__ ct,
                                                   const float* __restrict__ st,
                                                   unsigned short* __restrict__ kb) {
  int tid = blockIdx.x * 256 + threadIdx.x;   // < 2048*8*32
  int i = tid & 31;
  int h = (tid >> 5) & 7;
  int t = tid >> 8;
  const float* src = qkvf + (size_t)t * NQKV + NQ + h * 64;
  float x1 = src[i], x2 = src[i + 32];
  float c = ct[t * 32 + i], s = st[t * 32 + i];
  int b = t >> 10, sidx = t & 1023;
  unsigned short* dst = kb + (((size_t)(b * NKV + h)) * SS + sidx) * HD;
  dst[i]      = f2b(x1 * c - x2 * s);
  dst[i + 32] = f2b(x1 * s + x2 * c);
}

// ---- GEMM: C[M][ldc] (fp32) = A_bf16[M][K] * Bt_bf16[N][K]^T  (m97 structure) ----
__global__ __launch_bounds__(256) void gemm_bt(const unsigned short* __restrict__ A,
                                               const unsigned short* __restrict__ Bt,
                                               float* __restrict__ C,
                                               int K, int ldc, int Nvalid) {
  __shared__ unsigned short lA[128 * 32];
  __shared__ unsigned short lB[128 * 32];
  const int tid = threadIdx.x;
  const int lane = tid & 63;
  const int w = tid >> 6;
  const int wm = (w >> 1) * 64, wn = (w & 1) * 64;
  const int bm = blockIdx.y * 128, bn = blockIdx.x * 128;
  const int m16 = lane & 15, g4 = lane >> 4;
  f32x4 acc[4][4];
#pragma unroll
  for (int i = 0; i < 4; ++i)
#pragma unroll
    for (int j = 0; j < 4; ++j) acc[i][j] = (f32x4){0.f, 0.f, 0.f, 0.f};
  const int srow = tid >> 2;
  const int scol = (tid & 3) * 8;
  const unsigned short* ga = A + (size_t)(bm + srow) * K + scol;
  const unsigned short* gb = Bt + (size_t)(bn + srow) * K + scol;
  const int lw = (tid >> 6) * 512;   // wave-uniform LDS elem offset
  const int nk = K >> 5;
  for (int kt = 0; kt < nk; ++kt) {
    const int ko = kt * 32;
    __syncthreads();
    gload16(ga + ko,                  lA + lw);
    gload16(ga + (size_t)64 * K + ko, lA + 2048 + lw);
    gload16(gb + ko,                  lB + lw);
    gload16(gb + (size_t)64 * K + ko, lB + 2048 + lw);
    __syncthreads();
    short8 af[4], bfr[4];
#pragma unroll
    for (int mi = 0; mi < 4; ++mi)
      af[mi] = *(const short8*)(lA + (wm + mi * 16 + m16) * 32 + g4 * 8);
#pragma unroll
    for (int ni = 0; ni < 4; ++ni)
      bfr[ni] = *(const short8*)(lB + (wn + ni * 16 + m16) * 32 + g4 * 8);
#pragma unroll
    for (int mi = 0; mi < 4; ++mi)
#pragma unroll
      for (int ni = 0; ni < 4; ++ni)
        acc[mi][ni] = __builtin_amdgcn_mfma_f32_16x16x32_bf16(af[mi], bfr[ni], acc[mi][ni], 0, 0, 0);
  }
  const int r0 = g4 * 4;
#pragma unroll
  for (int mi = 0; mi < 4; ++mi)
#pragma unroll
    for (int ni = 0; ni < 4; ++ni) {
      const int col = bn + wn + ni * 16 + m16;
      if (col < Nvalid) {
        const int row = bm + wm + mi * 16 + r0;
#pragma unroll
        for (int r = 0; r < 4; ++r)
          C[(size_t)(row + r) * ldc + col] = acc[mi][ni][r];
      }
    }
}

// ---- flash attention v2 (causal, GQA) ----
// grid (16 q-tiles, 128 b*h), block 256 (4 waves x 16 q-rows each), KVBLK=64.
// No barriers (per-wave P tile). P LDS tile [16][64] bf16 XOR-swizzled.
// Row-sum via MFMA with ones-B; row-max reduce only when defer-max gate fires.
__global__ __launch_bounds__(256) void attn_fwd(const unsigned short* __restrict__ qb,
                                                const unsigned short* __restrict__ kb,
                                                const unsigned short* __restrict__ vtb,
                                                unsigned short* __restrict__ ao) {
  __shared__ unsigned short pl[4][1024];   // 4 waves x [16][64] bf16 (swizzled)
  const int tid = threadIdx.x, lane = tid & 63, w = tid >> 6;
  const int qt = blockIdx.x;
  const int bh = blockIdx.y;
  const int b = bh >> 6, h = bh & 63, hkv = h >> 3;
  const int m16 = lane & 15, g4 = lane >> 4;
  const int qrow0 = qt * 64 + w * 16;

  const unsigned short* qp =
      qb + (((size_t)(b * NH + h)) * SS + qrow0 + m16) * HD + g4 * 8;
  short8 q0 = *(const short8*)(qp);
  short8 q1 = *(const short8*)(qp + 32);
  const unsigned short* kbp = kb + ((size_t)(b * NKV + hkv)) * SS * HD;
  const unsigned short* vbp = vtb + ((size_t)(b * NKV + hkv)) * HD * SS;

  const short8 ones = {(short)0x3F80, (short)0x3F80, (short)0x3F80, (short)0x3F80,
                       (short)0x3F80, (short)0x3F80, (short)0x3F80, (short)0x3F80};

  f32x4 o[4];
#pragma unroll
  for (int n = 0; n < 4; ++n) o[n] = (f32x4){0.f, 0.f, 0.f, 0.f};
  f32x4 lacc = (f32x4){0.f, 0.f, 0.f, 0.f};
  float mrow[4] = {-1e30f, -1e30f, -1e30f, -1e30f};
  const int rbase = qrow0 + g4 * 4;
  char* pw = (char*)pl[w];
  // read offsets (row = m16, cols g4*8.. , +32)
  const int rd0 = (m16 * 128 + g4 * 16) ^ ((m16 & 7) << 4);
  const int rd1 = (m16 * 128 + 64 + g4 * 16) ^ ((m16 & 7) << 4);

  for (int t = 0; t <= qt; ++t) {
    const int k0 = t * 64;
    f32x4 s[4];
#pragma unroll
    for (int f = 0; f < 4; ++f) {
      const unsigned short* kr = kbp + (size_t)(k0 + f * 16 + m16) * HD + g4 * 8;
      short8 ka = *(const short8*)(kr);
      short8 kc = *(const short8*)(kr + 32);
      f32x4 z = (f32x4){0.f, 0.f, 0.f, 0.f};
      z = __builtin_amdgcn_mfma_f32_16x16x32_bf16(q0, ka, z, 0, 0, 0);
      z = __builtin_amdgcn_mfma_f32_16x16x32_bf16(q1, kc, z, 0, 0, 0);
      s[f] = z;
    }
    if (t == qt) {   // diagonal tile: causal mask
#pragma unroll
      for (int f = 0; f < 4; ++f)
#pragma unroll
        for (int r = 0; r < 4; ++r)
          if (k0 + f * 16 + m16 > rbase + r) s[f][r] = -1e30f;
    }
    // defer-max gate: per-lane test, no reduce needed to defer
    int grow = 0;
#pragma unroll
    for (int f = 0; f < 4; ++f)
#pragma unroll
      for (int r = 0; r < 4; ++r)
        grow |= (s[f][r] > mrow[r] + 8.f);
    if (__any(grow)) {
      float mx[4];
#pragma unroll
      for (int r = 0; r < 4; ++r)
        mx[r] = fmaxf(fmaxf(s[0][r], s[1][r]), fmaxf(s[2][r], s[3][r]));
#pragma unroll
      for (int off = 1; off <= 8; off <<= 1)
#pragma unroll
        for (int r = 0; r < 4; ++r) mx[r] = fmaxf(mx[r], __shfl_xor(mx[r], off));
#pragma unroll
      for (int r = 0; r < 4; ++r) {
        float mn = fmaxf(mrow[r], mx[r]);
        float sc = __expf(mrow[r] - mn);
        mrow[r] = mn;
        lacc[r] *= sc;
#pragma unroll
        for (int n = 0; n < 4; ++n) o[n][r] *= sc;
      }
    }
    // P = exp(s - mrow) -> bf16 -> swizzled LDS
#pragma unroll
    for (int f = 0; f < 4; ++f)
#pragma unroll
      for (int r = 0; r < 4; ++r) {
        unsigned short pv = f2b(__expf(s[f][r] - mrow[r]));
        int row = g4 * 4 + r;
        int byte = (row * 128 + (f * 16 + m16) * 2) ^ ((row & 7) << 4);
        *(unsigned short*)(pw + byte) = pv;
      }
    short8 pf0 = *(const short8*)(pw + rd0);
    short8 pf1 = *(const short8*)(pw + rd1);
    lacc = __builtin_amdgcn_mfma_f32_16x16x32_bf16(pf0, ones, lacc, 0, 0, 0);
    lacc = __builtin_amdgcn_mfma_f32_16x16x32_bf16(pf1, ones, lacc, 0, 0, 0);
#pragma unroll
    for (int n = 0; n < 4; ++n) {
      const unsigned short* vr = vbp + (size_t)(n * 16 + m16) * SS + k0 + g4 * 8;
      short8 vf0 = *(const short8*)(vr);
      short8 vf1 = *(const short8*)(vr + 32);
      o[n] = __builtin_amdgcn_mfma_f32_16x16x32_bf16(pf0, vf0, o[n], 0, 0, 0);
      o[n] = __builtin_amdgcn_mfma_f32_16x16x32_bf16(pf1, vf1, o[n], 0, 0, 0);
    }
  }

  float inv[4];
#pragma unroll
  for (int r = 0; r < 4; ++r) inv[r] = 1.f / lacc[r];
  const size_t row0 = (size_t)b * SS + qrow0 + g4 * 4;
#pragma unroll
  for (int n = 0; n < 4; ++n)
#pragma unroll
    for (int r = 0; r < 4; ++r)
      ao[(row0 + r) * (size_t)NQ + h * 64 + n * 16 + m16] = f2b(o[n][r] * inv[r]);
}

// ---- workspace layout (bytes) ----
constexpr size_t OFF_XB    = 0;                          // 2048*2880*2   = 11796480
constexpr size_t OFF_WQKVT = 11796480;                   // 5120*2880*2   = 29491200
constexpr size_t OFF_WOT   = OFF_WQKVT + 29491200;       // 2944*4096*2   = 24117248
constexpr size_t OFF_COS   = OFF_WOT + 24117248;         // 2048*32*4     = 262144
constexpr size_t OFF_SIN   = OFF_COS + 262144;
constexpr size_t OFF_QKVF  = OFF_SIN + 262144;           // 2048*5120*4   = 41943040
constexpr size_t OFF_QB    = OFF_QKVF + 41943040;        // 2*64*1024*64*2 = 16777216
constexpr size_t OFF_KB    = OFF_QB + 16777216;          // 2*8*1024*64*2  = 2097152
constexpr size_t OFF_VTB   = OFF_KB + 2097152;           // 2097152; end = 128843776

extern "C" void kernel_launch(void* const* d_in, const int* in_sizes, int n_in,
                              void* d_out, int out_size, void* d_ws, size_t ws_size,
                              hipStream_t stream) {
  const float* x  = (const float*)d_in[0];
  const float* wq = (const float*)d_in[1];
  const float* wk = (const float*)d_in[2];
  const float* wv = (const float*)d_in[3];
  const float* wo = (const float*)d_in[4];
  const int* pos  = (const int*)d_in[5];
  float* out = (float*)d_out;
  char* ws = (char*)d_ws;

  unsigned short* xb    = (unsigned short*)(ws + OFF_XB);
  unsigned short* wqkvt = (unsigned short*)(ws + OFF_WQKVT);
  unsigned short* wot   = (unsigned short*)(ws + OFF_WOT);
  float* ct             = (float*)(ws + OFF_COS);
  float* st             = (float*)(ws + OFF_SIN);
  float* qkvf           = (float*)(ws + OFF_QKVF);
  unsigned short* qb    = (unsigned short*)(ws + OFF_QB);
  unsigned short* kb    = (unsigned short*)(ws + OFF_KB);
  unsigned short* vtb   = (unsigned short*)(ws + OFF_VTB);
  unsigned short* attnb = (unsigned short*)(ws + OFF_QKVF);  // reuse qkvf region

  cast_x_kernel<<<(M_TOK * HIDDEN / 4 + 255) / 256, 256, 0, stream>>>(x, xb, M_TOK * HIDDEN / 4);
  rope_table<<<(M_TOK * 32) / 256, 256, 0, stream>>>(pos, ct, st);
  transpose_cast<<<dim3(NQ / 32, HIDDEN / 32), dim3(32, 8), 0, stream>>>(
      wq, NQ, wqkvt, HIDDEN, NQ);
  transpose_cast<<<dim3(NKVD / 32, HIDDEN / 32), dim3(32, 8), 0, stream>>>(
      wk, NKVD, wqkvt + (size_t)NQ * HIDDEN, HIDDEN, NKVD);
  transpose_cast<<<dim3(NKVD / 32, HIDDEN / 32), dim3(32, 8), 0, stream>>>(
      wv, NKVD, wqkvt + (size_t)(NQ + NKVD) * HIDDEN, HIDDEN, NKVD);
  transpose_cast<<<dim3(NOUT_PAD / 32, NQ / 32), dim3(32, 8), 0, stream>>>(
      wo, NOUT, wot, NQ, NOUT);
  gemm_bt<<<dim3(NQKV / 128, M_TOK / 128), 256, 0, stream>>>(
      xb, wqkvt, qkvf, HIDDEN, NQKV, NQKV);
  rope_q_pack<<<(M_TOK * NH * 32) / 256, 256, 0, stream>>>(qkvf, ct, st, qb);
  rope_k_pack<<<(M_TOK * NKV * 32) / 256, 256, 0, stream>>>(qkvf, ct, st, kb);
  for (int b = 0; b < BB; ++b)
    transpose_cast<<<dim3(NKVD / 32, SS / 32), dim3(32, 8), 0, stream>>>(
        qkvf + (size_t)b * SS * NQKV + (NQ + NKVD), NQKV,
        vtb + (size_t)b * NKVD * SS, SS, NKVD);
  attn_fwd<<<dim3(SS / 64, BB * NH), 256, 0, stream>>>(qb, kb, vtb, attnb);
  gemm_bt<<<dim3(NOUT_PAD / 128, M_TOK / 128), 256, 0, stream>>>(
      attnb, wot, out, NQ, NOUT, NOUT);
}

// Round 3
// 331.845 us; speedup vs baseline: 1.4750x; 1.4698x over previous
//
#include <hip/hip_runtime.h>

// ---- problem constants ----
#define BB 2
#define SS 1024
#define HIDDEN 2880
#define NH 64
#define NKV 8
#define HD 64
#define M_TOK 2048          // B*S
#define NQ 4096             // NH*HD
#define NKVD 512            // NKV*HD
#define NQKV 5120           // NQ + 2*NKVD
#define NOUT 2880
#define NOUT_PAD 2944       // 23*128

typedef __attribute__((ext_vector_type(8))) short short8;
typedef __attribute__((ext_vector_type(4))) float f32x4;

__device__ __forceinline__ unsigned short f2b(float x) {
  union { float f; unsigned u; } v; v.f = x;
  unsigned r = (v.u + 0x7FFFu + ((v.u >> 16) & 1u)) >> 16;
  return (unsigned short)r;
}

__device__ __forceinline__ void gload16(const void* g, void* l) {
  __builtin_amdgcn_global_load_lds(
      (const __attribute__((address_space(1))) void*)g,
      (__attribute__((address_space(3))) void*)l, 16, 0, 0);
}

// ---- cast x (fp32 -> bf16), vectorized ----
__global__ __launch_bounds__(256) void cast_x_kernel(const float* __restrict__ in,
                                                     unsigned short* __restrict__ out,
                                                     int n4) {
  int idx = blockIdx.x * 256 + threadIdx.x;
  if (idx >= n4) return;
  float4 v = ((const float4*)in)[idx];
  ushort4 o;
  o.x = f2b(v.x); o.y = f2b(v.y); o.z = f2b(v.z); o.w = f2b(v.w);
  ((ushort4*)out)[idx] = o;
}

// ---- transpose + cast: out[n*K + k] = (bf16) in[k*ldin + n] ----
__global__ __launch_bounds__(256) void transpose_cast(const float* __restrict__ in,
                                                      long ldin,
                                                      unsigned short* __restrict__ out,
                                                      int K, int N) {
  __shared__ float t[32][33];
  const int n0 = blockIdx.x * 32, k0 = blockIdx.y * 32;
  const int tx = threadIdx.x, ty = threadIdx.y;
#pragma unroll
  for (int i = 0; i < 4; ++i) {
    int k = k0 + ty + i * 8;
    int n = n0 + tx;
    t[ty + i * 8][tx] = (n < N) ? in[(long)k * ldin + n] : 0.f;
  }
  __syncthreads();
#pragma unroll
  for (int i = 0; i < 4; ++i) {
    int n = n0 + ty + i * 8;
    int k = k0 + tx;
    out[(long)n * K + k] = f2b(t[tx][ty + i * 8]);
  }
}

// ---- RoPE cos/sin table: [2048][32] each ----
__global__ __launch_bounds__(256) void rope_table(const int* __restrict__ pos,
                                                  float* __restrict__ ct,
                                                  float* __restrict__ st) {
  int tid = blockIdx.x * 256 + threadIdx.x;   // < 2048*32
  int t = tid >> 5, i = tid & 31;
  float p = (float)pos[t];
  float f = p * expf(-(float)i * (11.918390573078392f / 32.f));
  ct[tid] = cosf(f);
  st[tid] = sinf(f);
}

// ---- RoPE + pack q (pre-scaled by 1/8): -> qb[b][h][s][d] bf16 ----
__global__ __launch_bounds__(256) void rope_q_pack(const float* __restrict__ qkvf,
                                                   const float* __restrict__ ct,
                                                   const float* __restrict__ st,
                                                   unsigned short* __restrict__ qb) {
  int tid = blockIdx.x * 256 + threadIdx.x;   // < 2048*64*32
  int i = tid & 31;
  int h = (tid >> 5) & 63;
  int t = tid >> 11;
  const float* src = qkvf + (size_t)t * NQKV + h * 64;
  float x1 = src[i], x2 = src[i + 32];
  float c = ct[t * 32 + i], s = st[t * 32 + i];
  int b = t >> 10, sidx = t & 1023;
  unsigned short* dst = qb + (((size_t)(b * NH + h)) * SS + sidx) * HD;
  dst[i]      = f2b((x1 * c - x2 * s) * 0.125f);
  dst[i + 32] = f2b((x1 * s + x2 * c) * 0.125f);
}

// ---- RoPE + pack k ----
__global__ __launch_bounds__(256) void rope_k_pack(const float* __restrict__ qkvf,
                                                   const float* __restrict__ ct,
                                                   const float* __restrict__ st,
                                                   unsigned short* __restrict__ kb) {
  int tid = blockIdx.x * 256 + threadIdx.x;   // < 2048*8*32
  int i = tid & 31;
  int h = (tid >> 5) & 7;
  int t = tid >> 8;
  const float* src = qkvf + (size_t)t * NQKV + NQ + h * 64;
  float x1 = src[i], x2 = src[i + 32];
  float c = ct[t * 32 + i], s = st[t * 32 + i];
  int b = t >> 10, sidx = t & 1023;
  unsigned short* dst = kb + (((size_t)(b * NKV + h)) * SS + sidx) * HD;
  dst[i]      = f2b(x1 * c - x2 * s);
  dst[i + 32] = f2b(x1 * s + x2 * c);
}

// ---- GEMM: C[M][ldc] (fp32) = A_bf16[M][K] * Bt_bf16[N][K]^T  (m97 structure) ----
__global__ __launch_bounds__(256) void gemm_bt(const unsigned short* __restrict__ A,
                                               const unsigned short* __restrict__ Bt,
                                               float* __restrict__ C,
                                               int K, int ldc, int Nvalid) {
  __shared__ unsigned short lA[128 * 32];
  __shared__ unsigned short lB[128 * 32];
  const int tid = threadIdx.x;
  const int lane = tid & 63;
  const int w = tid >> 6;
  const int wm = (w >> 1) * 64, wn = (w & 1) * 64;
  const int bm = blockIdx.y * 128, bn = blockIdx.x * 128;
  const int m16 = lane & 15, g4 = lane >> 4;
  f32x4 acc[4][4];
#pragma unroll
  for (int i = 0; i < 4; ++i)
#pragma unroll
    for (int j = 0; j < 4; ++j) acc[i][j] = (f32x4){0.f, 0.f, 0.f, 0.f};
  const int srow = tid >> 2;
  const int scol = (tid & 3) * 8;
  const unsigned short* ga = A + (size_t)(bm + srow) * K + scol;
  const unsigned short* gb = Bt + (size_t)(bn + srow) * K + scol;
  const int lw = (tid >> 6) * 512;
  const int nk = K >> 5;
  for (int kt = 0; kt < nk; ++kt) {
    const int ko = kt * 32;
    __syncthreads();
    gload16(ga + ko,                  lA + lw);
    gload16(ga + (size_t)64 * K + ko, lA + 2048 + lw);
    gload16(gb + ko,                  lB + lw);
    gload16(gb + (size_t)64 * K + ko, lB + 2048 + lw);
    __syncthreads();
    short8 af[4], bfr[4];
#pragma unroll
    for (int mi = 0; mi < 4; ++mi)
      af[mi] = *(const short8*)(lA + (wm + mi * 16 + m16) * 32 + g4 * 8);
#pragma unroll
    for (int ni = 0; ni < 4; ++ni)
      bfr[ni] = *(const short8*)(lB + (wn + ni * 16 + m16) * 32 + g4 * 8);
#pragma unroll
    for (int mi = 0; mi < 4; ++mi)
#pragma unroll
      for (int ni = 0; ni < 4; ++ni)
        acc[mi][ni] = __builtin_amdgcn_mfma_f32_16x16x32_bf16(af[mi], bfr[ni], acc[mi][ni], 0, 0, 0);
  }
  const int r0 = g4 * 4;
#pragma unroll
  for (int mi = 0; mi < 4; ++mi)
#pragma unroll
    for (int ni = 0; ni < 4; ++ni) {
      const int col = bn + wn + ni * 16 + m16;
      if (col < Nvalid) {
        const int row = bm + wm + mi * 16 + r0;
#pragma unroll
        for (int r = 0; r < 4; ++r)
          C[(size_t)(row + r) * ldc + col] = acc[mi][ni][r];
      }
    }
}

// ---- flash attention v3: 8 waves/block, LDS-staged K/V, double-buffered ----
// grid (4 q-blocks of 256 rows, 128 b*h), block 512.
// K tile [64][64] bf16 + V^T tile [64][64] bf16, both XOR-swizzled
// (linear LDS dest + pre-swizzled global src for global_load_lds).
__global__ __launch_bounds__(512) void attn_fwd(const unsigned short* __restrict__ qb,
                                                const unsigned short* __restrict__ kb,
                                                const unsigned short* __restrict__ vtb,
                                                unsigned short* __restrict__ ao) {
  __shared__ unsigned short kB[2][64 * 64];   // 8KB each buf
  __shared__ unsigned short vB[2][64 * 64];
  __shared__ unsigned short pB[8][32 * 64];   // 4KB per wave
  const int tid = threadIdx.x, lane = tid & 63, w = tid >> 6;
  const int qblk = blockIdx.x;
  const int bh = blockIdx.y;
  const int b = bh >> 6, h = bh & 63, hkv = h >> 3;
  const int m16 = lane & 15, g4 = lane >> 4;
  const int rbase = qblk * 256 + w * 32;      // this wave's first q-row

  // Q fragments: 2 row-frags x 2 d-halves (pre-scaled by 1/8 in qb)
  const unsigned short* qp =
      qb + (((size_t)(b * NH + h)) * SS + rbase + m16) * HD + g4 * 8;
  const short8 q00 = *(const short8*)(qp);
  const short8 q01 = *(const short8*)(qp + 32);
  const short8 q10 = *(const short8*)(qp + 16 * HD);
  const short8 q11 = *(const short8*)(qp + 16 * HD + 32);

  const char* kbp = (const char*)(kb + ((size_t)(b * NKV + hkv)) * SS * HD);
  const char* vbp = (const char*)(vtb + ((size_t)(b * NKV + hkv)) * HD * SS);

  // staging: wave w stages rows w*8..w*8+7 of the 64-row tile (1 gload each for K,V)
  const int lrow = lane >> 3;                                    // 0..7
  const int lcolb = ((lane & 7) * 16) ^ ((lrow & 7) << 4);       // pre-swizzled col byte
  unsigned short* kDst0 = &kB[0][w * 512];
  unsigned short* kDst1 = &kB[1][w * 512];
  unsigned short* vDst0 = &vB[0][w * 512];
  unsigned short* vDst1 = &vB[1][w * 512];
  const size_t kRowOff = (size_t)(w * 8 + lrow) * 128 + lcolb;   // bytes within K tile
  const size_t vRowOff = (size_t)(w * 8 + lrow) * 2048 + lcolb;  // V^T row stride 2KB

  const short8 ones = {(short)0x3F80, (short)0x3F80, (short)0x3F80, (short)0x3F80,
                       (short)0x3F80, (short)0x3F80, (short)0x3F80, (short)0x3F80};

  f32x4 o0[4], o1[4];
#pragma unroll
  for (int n = 0; n < 4; ++n) { o0[n] = (f32x4){0,0,0,0}; o1[n] = (f32x4){0,0,0,0}; }
  f32x4 lacc0 = (f32x4){0,0,0,0}, lacc1 = (f32x4){0,0,0,0};
  float mrow0[4] = {-1e30f,-1e30f,-1e30f,-1e30f};
  float mrow1[4] = {-1e30f,-1e30f,-1e30f,-1e30f};

  char* pw = (char*)pB[w];
  const int swz_m = (m16 & 7) << 4;
  const int nt = (qblk + 1) * 4;

  // prologue: stage tile 0 into buf 0
  gload16(kbp + kRowOff, kDst0);
  gload16(vbp + vRowOff, vDst0);
  __syncthreads();

  for (int t = 0; t < nt; ++t) {
    const int k0 = t * 64;
    const char* kLds = (const char*)kB[t & 1];
    const char* vLds = (const char*)vB[t & 1];
    // stage next tile into the other buffer
    if (t + 1 < nt) {
      if (t & 1) { gload16(kbp + (size_t)(t + 1) * 8192 + kRowOff, kDst0);
                   gload16(vbp + (size_t)(t + 1) * 128  + vRowOff, vDst0); }
      else       { gload16(kbp + (size_t)(t + 1) * 8192 + kRowOff, kDst1);
                   gload16(vbp + (size_t)(t + 1) * 128  + vRowOff, vDst1); }
    }
    if (k0 < rbase + 32) {   // wave has at least one unmasked row
      // K B-fragments (swizzled read)
      short8 kf0[4], kf1[4];
#pragma unroll
      for (int kf = 0; kf < 4; ++kf) {
        const int rb = (kf * 16 + m16) * 128;
        kf0[kf] = *(const short8*)(kLds + ((rb + g4 * 16) ^ swz_m));
        kf1[kf] = *(const short8*)(kLds + ((rb + 64 + g4 * 16) ^ swz_m));
      }
      f32x4 s0[4], s1[4];
      __builtin_amdgcn_s_setprio(1);
#pragma unroll
      for (int kf = 0; kf < 4; ++kf) {
        f32x4 z = (f32x4){0,0,0,0};
        z = __builtin_amdgcn_mfma_f32_16x16x32_bf16(q00, kf0[kf], z, 0, 0, 0);
        z = __builtin_amdgcn_mfma_f32_16x16x32_bf16(q01, kf1[kf], z, 0, 0, 0);
        s0[kf] = z;
        f32x4 z2 = (f32x4){0,0,0,0};
        z2 = __builtin_amdgcn_mfma_f32_16x16x32_bf16(q10, kf0[kf], z2, 0, 0, 0);
        z2 = __builtin_amdgcn_mfma_f32_16x16x32_bf16(q11, kf1[kf], z2, 0, 0, 0);
        s1[kf] = z2;
      }
      __builtin_amdgcn_s_setprio(0);
      // causal mask (only near diagonal)
      if (k0 + 63 >= rbase) {
#pragma unroll
        for (int kf = 0; kf < 4; ++kf)
#pragma unroll
          for (int r = 0; r < 4; ++r) {
            const int col = k0 + kf * 16 + m16;
            if (col > rbase + g4 * 4 + r)      s0[kf][r] = -1e30f;
            if (col > rbase + 16 + g4 * 4 + r) s1[kf][r] = -1e30f;
          }
      }
      // defer-max gate
      int grow = 0;
#pragma unroll
      for (int kf = 0; kf < 4; ++kf)
#pragma unroll
        for (int r = 0; r < 4; ++r) {
          grow |= (s0[kf][r] > mrow0[r] + 8.f);
          grow |= (s1[kf][r] > mrow1[r] + 8.f);
        }
      if (__any(grow)) {
        float mx0[4], mx1[4];
#pragma unroll
        for (int r = 0; r < 4; ++r) {
          mx0[r] = fmaxf(fmaxf(s0[0][r], s0[1][r]), fmaxf(s0[2][r], s0[3][r]));
          mx1[r] = fmaxf(fmaxf(s1[0][r], s1[1][r]), fmaxf(s1[2][r], s1[3][r]));
        }
#pragma unroll
        for (int off = 1; off <= 8; off <<= 1)
#pragma unroll
          for (int r = 0; r < 4; ++r) {
            mx0[r] = fmaxf(mx0[r], __shfl_xor(mx0[r], off));
            mx1[r] = fmaxf(mx1[r], __shfl_xor(mx1[r], off));
          }
#pragma unroll
        for (int r = 0; r < 4; ++r) {
          float mn0 = fmaxf(mrow0[r], mx0[r]);
          float sc0 = __expf(mrow0[r] - mn0);
          mrow0[r] = mn0; lacc0[r] *= sc0;
          float mn1 = fmaxf(mrow1[r], mx1[r]);
          float sc1 = __expf(mrow1[r] - mn1);
          mrow1[r] = mn1; lacc1[r] *= sc1;
#pragma unroll
          for (int n = 0; n < 4; ++n) { o0[n][r] *= sc0; o1[n][r] *= sc1; }
        }
      }
      // P = exp(s - m) -> bf16 -> swizzled per-wave LDS
#pragma unroll
      for (int kf = 0; kf < 4; ++kf)
#pragma unroll
        for (int r = 0; r < 4; ++r) {
          const int colb = (kf * 16 + m16) * 2;
          int row = g4 * 4 + r;
          *(unsigned short*)(pw + ((row * 128 + colb) ^ ((row & 7) << 4))) =
              f2b(__expf(s0[kf][r] - mrow0[r]));
          row += 16;
          *(unsigned short*)(pw + ((row * 128 + colb) ^ ((row & 7) << 4))) =
              f2b(__expf(s1[kf][r] - mrow1[r]));
        }
      // P A-frags + V^T B-frags -> PV and row-sum MFMAs
      const int prb0 = m16 * 128, prb1 = (16 + m16) * 128;
      short8 pf00 = *(const short8*)(pw + ((prb0 + g4 * 16) ^ swz_m));
      short8 pf01 = *(const short8*)(pw + ((prb0 + 64 + g4 * 16) ^ swz_m));
      short8 pf10 = *(const short8*)(pw + ((prb1 + g4 * 16) ^ swz_m));
      short8 pf11 = *(const short8*)(pw + ((prb1 + 64 + g4 * 16) ^ swz_m));
      __builtin_amdgcn_s_setprio(1);
      lacc0 = __builtin_amdgcn_mfma_f32_16x16x32_bf16(pf00, ones, lacc0, 0, 0, 0);
      lacc0 = __builtin_amdgcn_mfma_f32_16x16x32_bf16(pf01, ones, lacc0, 0, 0, 0);
      lacc1 = __builtin_amdgcn_mfma_f32_16x16x32_bf16(pf10, ones, lacc1, 0, 0, 0);
      lacc1 = __builtin_amdgcn_mfma_f32_16x16x32_bf16(pf11, ones, lacc1, 0, 0, 0);
#pragma unroll
      for (int n = 0; n < 4; ++n) {
        const int rb = (n * 16 + m16) * 128;
        short8 vf0 = *(const short8*)(vLds + ((rb + g4 * 16) ^ swz_m));
        short8 vf1 = *(const short8*)(vLds + ((rb + 64 + g4 * 16) ^ swz_m));
        o0[n] = __builtin_amdgcn_mfma_f32_16x16x32_bf16(pf00, vf0, o0[n], 0, 0, 0);
        o0[n] = __builtin_amdgcn_mfma_f32_16x16x32_bf16(pf01, vf1, o0[n], 0, 0, 0);
        o1[n] = __builtin_amdgcn_mfma_f32_16x16x32_bf16(pf10, vf0, o1[n], 0, 0, 0);
        o1[n] = __builtin_amdgcn_mfma_f32_16x16x32_bf16(pf11, vf1, o1[n], 0, 0, 0);
      }
      __builtin_amdgcn_s_setprio(0);
    }
    __syncthreads();   // drains vmcnt for staged loads + syncs buffers
  }

  float inv0[4], inv1[4];
#pragma unroll
  for (int r = 0; r < 4; ++r) { inv0[r] = 1.f / lacc0[r]; inv1[r] = 1.f / lacc1[r]; }
  const size_t row0 = (size_t)b * SS + rbase + g4 * 4;
#pragma unroll
  for (int n = 0; n < 4; ++n)
#pragma unroll
    for (int r = 0; r < 4; ++r) {
      ao[(row0 + r) * (size_t)NQ + h * 64 + n * 16 + m16] = f2b(o0[n][r] * inv0[r]);
      ao[(row0 + 16 + r) * (size_t)NQ + h * 64 + n * 16 + m16] = f2b(o1[n][r] * inv1[r]);
    }
}

// ---- workspace layout (bytes) ----
constexpr size_t OFF_XB    = 0;
constexpr size_t OFF_WQKVT = 11796480;
constexpr size_t OFF_WOT   = OFF_WQKVT + 29491200;
constexpr size_t OFF_COS   = OFF_WOT + 24117248;
constexpr size_t OFF_SIN   = OFF_COS + 262144;
constexpr size_t OFF_QKVF  = OFF_SIN + 262144;
constexpr size_t OFF_QB    = OFF_QKVF + 41943040;
constexpr size_t OFF_KB    = OFF_QB + 16777216;
constexpr size_t OFF_VTB   = OFF_KB + 2097152;

extern "C" void kernel_launch(void* const* d_in, const int* in_sizes, int n_in,
                              void* d_out, int out_size, void* d_ws, size_t ws_size,
                              hipStream_t stream) {
  const float* x  = (const float*)d_in[0];
  const float* wq = (const float*)d_in[1];
  const float* wk = (const float*)d_in[2];
  const float* wv = (const float*)d_in[3];
  const float* wo = (const float*)d_in[4];
  const int* pos  = (const int*)d_in[5];
  float* out = (float*)d_out;
  char* ws = (char*)d_ws;

  unsigned short* xb    = (unsigned short*)(ws + OFF_XB);
  unsigned short* wqkvt = (unsigned short*)(ws + OFF_WQKVT);
  unsigned short* wot   = (unsigned short*)(ws + OFF_WOT);
  float* ct             = (float*)(ws + OFF_COS);
  float* st             = (float*)(ws + OFF_SIN);
  float* qkvf           = (float*)(ws + OFF_QKVF);
  unsigned short* qbuf  = (unsigned short*)(ws + OFF_QB);
  unsigned short* kbuf  = (unsigned short*)(ws + OFF_KB);
  unsigned short* vtb   = (unsigned short*)(ws + OFF_VTB);
  unsigned short* attnb = (unsigned short*)(ws + OFF_QKVF);  // reuse qkvf region

  cast_x_kernel<<<(M_TOK * HIDDEN / 4 + 255) / 256, 256, 0, stream>>>(x, xb, M_TOK * HIDDEN / 4);
  rope_table<<<(M_TOK * 32) / 256, 256, 0, stream>>>(pos, ct, st);
  transpose_cast<<<dim3(NQ / 32, HIDDEN / 32), dim3(32, 8), 0, stream>>>(
      wq, NQ, wqkvt, HIDDEN, NQ);
  transpose_cast<<<dim3(NKVD / 32, HIDDEN / 32), dim3(32, 8), 0, stream>>>(
      wk, NKVD, wqkvt + (size_t)NQ * HIDDEN, HIDDEN, NKVD);
  transpose_cast<<<dim3(NKVD / 32, HIDDEN / 32), dim3(32, 8), 0, stream>>>(
      wv, NKVD, wqkvt + (size_t)(NQ + NKVD) * HIDDEN, HIDDEN, NKVD);
  transpose_cast<<<dim3(NOUT_PAD / 32, NQ / 32), dim3(32, 8), 0, stream>>>(
      wo, NOUT, wot, NQ, NOUT);
  gemm_bt<<<dim3(NQKV / 128, M_TOK / 128), 256, 0, stream>>>(
      xb, wqkvt, qkvf, HIDDEN, NQKV, NQKV);
  rope_q_pack<<<(M_TOK * NH * 32) / 256, 256, 0, stream>>>(qkvf, ct, st, qbuf);
  rope_k_pack<<<(M_TOK * NKV * 32) / 256, 256, 0, stream>>>(qkvf, ct, st, kbuf);
  for (int b = 0; b < BB; ++b)
    transpose_cast<<<dim3(NKVD / 32, SS / 32), dim3(32, 8), 0, stream>>>(
        qkvf + (size_t)b * SS * NQKV + (NQ + NKVD), NQKV,
        vtb + (size_t)b * NKVD * SS, SS, NKVD);
  attn_fwd<<<dim3(4, BB * NH), 512, 0, stream>>>(qbuf, kbuf, vtb, attnb);
  gemm_bt<<<dim3(NOUT_PAD / 128, M_TOK / 128), 256, 0, stream>>>(
      attnb, wot, out, NQ, NOUT, NOUT);
}